// Round 7
// baseline (336.165 us; speedup 1.0000x reference)
//
#include <hip/hip_runtime.h>
#include <hip/hip_bf16.h>
#include <hip/hip_cooperative_groups.h>

// MinGRU: L=2 layers of  h_t = (1-z_t) h_{t-1} + z_t g(pre_t)
// R10: the GEMM K-loop is LDS-read-throughput-bound (16 ds_read_b128 x 12cyc
//      per wave per K-step = ~82us/CU = R3's whole wall time). Fix: stream the
//      B-operands (Wz/Wh, L2-resident) directly from global into registers
//      with per-lane fragment addresses (bit-identical bytes to the LDS path),
//      issued between the staging barriers so L2 latency hides under the
//      A-staging drain. W staging removed (LDS 32->16.6KB, async16 8->4/wave),
//      K-loop LDS reads halved. Coop wrapper / Phase C / cast unchanged (R9).

#define L_ 2
#define B_ 8
#define S_ 2048
#define D_ 1024
#define H_ 1024
#define M_ (B_*S_)     // 16384
#define NC 32          // chunks per sequence
#define CL (S_/NC)     // 64 steps per chunk

typedef __bf16    bf16x8 __attribute__((ext_vector_type(8)));
typedef float     f32x4  __attribute__((ext_vector_type(4)));
typedef _Float16  h2     __attribute__((ext_vector_type(2)));
typedef _Float16  h8     __attribute__((ext_vector_type(8)));

__device__ __forceinline__ ushort f2bf(float f) {
    union { __hip_bfloat16 h; ushort u; } c;
    c.h = __float2bfloat16(f);   // RNE
    return c.u;
}

__device__ __forceinline__ void async16(const void* g, void* l) {
    __builtin_amdgcn_global_load_lds(
        (const __attribute__((address_space(1))) unsigned int*)g,
        (__attribute__((address_space(3))) unsigned int*)l, 16, 0, 0);
}

// Single fused cast: x (M*D f32->bf16) and, for the low i-range, Wz/Wh too.
__global__ __launch_bounds__(256) void cast_all(const float* __restrict__ x,
                                                const float* __restrict__ Wz,
                                                const float* __restrict__ Wh,
                                                ushort* __restrict__ xb,
                                                ushort* __restrict__ wzb,
                                                ushort* __restrict__ whb) {
    const int nw = L_*H_*D_/4;                       // 524288
    int i = blockIdx.x * 256 + threadIdx.x;          // grid covers M_*D_/4
    {
        float4 v = ((const float4*)x)[i];
        ushort4 o;
        o.x = f2bf(v.x); o.y = f2bf(v.y); o.z = f2bf(v.z); o.w = f2bf(v.w);
        ((ushort4*)xb)[i] = o;
    }
    if (i < nw) {
        float4 v = ((const float4*)Wz)[i];
        ushort4 o;
        o.x = f2bf(v.x); o.y = f2bf(v.y); o.z = f2bf(v.z); o.w = f2bf(v.w);
        ((ushort4*)wzb)[i] = o;
        float4 w = ((const float4*)Wh)[i];
        ushort4 p;
        p.x = f2bf(w.x); p.y = f2bf(w.y); p.z = f2bf(w.z); p.w = f2bf(w.w);
        ((ushort4*)whb)[i] = p;
    }
}

// LDS layout (A staging): row R = 64 ushorts (8 chunks of 16B); logical chunk
// c stored at physical chunk c ^ (R&7).  Offset in ushorts:
#define SWZ(R, c) (((R) << 6) + ((((c) ^ ((R) & 7))) << 3))
#define MFMA16 __builtin_amdgcn_mfma_f32_16x16x32_bf16

// ======================= cooperative single-kernel path =====================
// 512 blocks x 256 thr, >=2 blocks/CU (static LDS 16.6 KiB).
// Phase A: rep=0..3, bid2 = blockIdx + rep*512 -> R3's exact tile mapping.
//   K-loop: stage A (4 async16/wave) | load 8 B-frags from global (L2) into
//   regs | barrier | 8 ds_read_b128 (A frags) + 32 MFMA.  B-frag bytes are
//   bit-identical to the old LDS path.
// grid.sync()
// Phase C: R6's fused chunk-prefix + replay + emit (2 items/thread).
__global__ __launch_bounds__(256, 2) void mingru_layer(const ushort* A,
                                                       const ushort* __restrict__ Wz,
                                                       const ushort* __restrict__ Wh,
                                                       const float* __restrict__ bz,
                                                       const float* __restrict__ bh,
                                                       h2* __restrict__ cv,
                                                       float* Ac,
                                                       float* Bc,
                                                       float* outf,
                                                       ushort* outb,
                                                       int write_bf16)
{
    __shared__ __align__(16) ushort sm[8320];        // 16.6 KiB static

    const int t    = threadIdx.x;
    const int lane = t & 63;
    const int wave = t >> 6;                         // 0..3
    const int lrow = lane & 15;
    const int lcq  = lane >> 4;                      // 0..3
    const int srow   = lane >> 3;                    // 0..7
    const int scol_g = (((lane & 7) ^ srow) << 3);   // swizzled source chunk
    const int colq = lane & 15;
    const int rowq = (lane >> 4) << 2;
    const int wm = (wave >> 1) * 64;                 // 0 / 64
    const int wn = (wave & 1) * 32;                  // 0 / 32

    // ---------------- Phase A: 4 reps of the GEMM ----------------
    for (int rep = 0; rep < 4; ++rep) {
        const int bid2 = (int)blockIdx.x + (rep << 9);
        const int xcd = bid2 & 7;
        const int k8  = bid2 >> 3;                   // 0..255
        const int nblk = k8 & 15;
        const int mblk = ((k8 >> 4) << 3) + xcd;     // 0..127
        const int m0 = mblk * 128;
        const int n0 = nblk * 64;

        f32x4 accz[4][2] = {};
        f32x4 acch[4][2] = {};

        for (int kb = 0; kb < D_; kb += 64) {
            __syncthreads();
            #pragma unroll
            for (int i = 0; i < 4; ++i) {            // A: 128 rows
                int r = i*32 + wave*8;
                async16(&A[(size_t)(m0 + r + srow)*D_ + kb + scol_g], &sm[r*64]);
            }
            // B fragments for this K-step straight from global (L2-hot W).
            // Bytes identical to the old LDS path:
            //   Wz[(n0+wn+nt*16+lrow)*D + kb + (kk*4+lcq)*8], 16B/lane.
            uint4 bzf[2][2], bhf[2][2];              // [kk][nt]
            #pragma unroll
            for (int kk = 0; kk < 2; ++kk)
                #pragma unroll
                for (int nt = 0; nt < 2; ++nt) {
                    const size_t wo = (size_t)(n0 + wn + nt*16 + lrow)*D_
                                      + kb + (kk*4 + lcq)*8;
                    bzf[kk][nt] = *(const uint4*)&Wz[wo];
                    bhf[kk][nt] = *(const uint4*)&Wh[wo];
                }
            __syncthreads();                         // drains vmcnt -> LDS+B ok
            #pragma unroll
            for (int kk = 0; kk < 2; ++kk) {
                const int cq = kk*4 + lcq;           // logical chunk 0..7
                bf16x8 af[4];
                #pragma unroll
                for (int mt = 0; mt < 4; ++mt) {
                    int R = wm + mt*16 + lrow;
                    uint4 u = *(const uint4*)&sm[SWZ(R, cq)];
                    af[mt] = __builtin_bit_cast(bf16x8, u);
                }
                #pragma unroll
                for (int nt = 0; nt < 2; ++nt) {
                    bf16x8 zb = __builtin_bit_cast(bf16x8, bzf[kk][nt]);
                    bf16x8 hb = __builtin_bit_cast(bf16x8, bhf[kk][nt]);
                    #pragma unroll
                    for (int mt = 0; mt < 4; ++mt) {
                        accz[mt][nt] = MFMA16(af[mt], zb, accz[mt][nt], 0, 0, 0);
                        acch[mt][nt] = MFMA16(af[mt], hb, acch[mt][nt], 0, 0, 0);
                    }
                }
            }
        }

        __syncthreads();                             // MFMA LDS reads done
        float2* seg = (float2*)sm;                   // [32 segs][stride 65]
        #pragma unroll
        for (int nt = 0; nt < 2; ++nt) {
            const int n = n0 + wn + nt*16 + colq;
            const float bzv = bz[n];
            const float bhv = bh[n];
            #pragma unroll
            for (int mt = 0; mt < 4; ++mt) {
                float a = 1.f, bb = 0.f;             // affine over lane's 4 rows
                h8 pk;
                #pragma unroll
                for (int r = 0; r < 4; ++r) {
                    float kx = accz[mt][nt][r] + bzv;
                    float p  = acch[mt][nt][r] + bhv;
                    float e   = __expf(-fabsf(kx));
                    float inv = 1.0f / (1.0f + e);
                    float z   = (kx >= 0.f) ? inv     : e * inv;
                    float c   = (kx >= 0.f) ? e * inv : inv;
                    float g;
                    if (p >= 0.f) g = p + 0.5f;
                    else { float eg = __expf(p); g = eg / (1.0f + eg); }
                    float v = z * g;
                    pk[2*r]     = (_Float16)c;
                    pk[2*r + 1] = (_Float16)v;
                    bb = fmaf(c, bb, v);
                    a *= c;
                }
                const int mb4 = (m0 + wm + mt*16 + rowq) >> 2;   // m&3 == r
                *(h8*)&cv[((size_t)mb4 * H_ + n) * 4] = pk;      // 16B coalesced
                const int sidx = (wm >> 2) + mt*4 + (rowq >> 2); // 0..31
                seg[sidx*65 + wn + nt*16 + colq] = make_float2(a, bb);
            }
        }
        __syncthreads();
        if (t < 128) {                               // chunk affines
            const int col  = t & 63;
            const int half = t >> 6;
            float a = 1.f, bb = 0.f;
            #pragma unroll
            for (int s = 0; s < 16; ++s) {
                float2 e2 = seg[(half*16 + s)*65 + col];
                bb = fmaf(e2.x, bb, e2.y);
                a *= e2.x;
            }
            const int b     = m0 >> 11;              // S = 2048
            const int chunk = ((m0 >> 6) & (NC - 1)) + half;
            const int qi = (b*NC + chunk)*H_ + n0 + col;
            Ac[qi] = a; Bc[qi] = bb;
        }
        // next rep's K-loop starts with __syncthreads -> seg reads complete
    }

    __threadfence();                                 // release cv/Ac/Bc
    cooperative_groups::this_grid().sync();

    // ---------------- Phase C: fused chunk-prefix + replay + emit ----------
    #pragma unroll
    for (int rep = 0; rep < 2; ++rep) {
        const int q = (int)blockIdx.x * 256 + t + rep * 131072;  // 0..262143
        const int h = q & (H_-1);
        const int c = (q >> 10) & (NC-1);
        const int b = q >> 15;
        float hc = 0.5f;                             // h0 = g(0) = 0.5
        for (int cp = 0; cp < c; ++cp) {
            int idx = (b*NC + cp)*H_ + h;
            hc = fmaf(Ac[idx], hc, Bc[idx]);
        }
        const int mb = b*S_ + c*CL;                  // base row (multiple of 4)
        if (write_bf16) {
            #pragma unroll 4
            for (int j = 0; j < 16; ++j) {
                h8 e = *(const h8*)&cv[(((size_t)(mb >> 2) + j)*H_ + h) * 4];
                #pragma unroll
                for (int u = 0; u < 4; ++u) {
                    hc = fmaf((float)e[2*u], hc, (float)e[2*u + 1]);
                    outb[(size_t)(mb + 4*j + u)*H_ + h] = f2bf(hc);
                }
            }
        } else {
            #pragma unroll 4
            for (int j = 0; j < 16; ++j) {
                h8 e = *(const h8*)&cv[(((size_t)(mb >> 2) + j)*H_ + h) * 4];
                #pragma unroll
                for (int u = 0; u < 4; ++u) {
                    hc = fmaf((float)e[2*u], hc, (float)e[2*u + 1]);
                    outf[(size_t)(mb + 4*j + u)*H_ + h] = hc;
                }
            }
        }
    }
}

// =========================== fallback path (R3/R6) ==========================
__global__ __launch_bounds__(256) void gemm_fb(const ushort* __restrict__ A,
                                               const ushort* __restrict__ Wz,
                                               const ushort* __restrict__ Wh,
                                               const float* __restrict__ bz,
                                               const float* __restrict__ bh,
                                               h2* __restrict__ cv,
                                               float* __restrict__ Ac,
                                               float* __restrict__ Bc)
{
    __shared__ __align__(16) ushort sm[16384];       // 32 KiB

    const int t    = threadIdx.x;
    const int lane = t & 63;
    const int wave = t >> 6;
    const int xcd = (int)blockIdx.x & 7;
    const int k8  = (int)blockIdx.x >> 3;            // 0..255
    const int nblk = k8 & 15;
    const int mblk = ((k8 >> 4) << 3) + xcd;         // 0..127
    const int m0 = mblk * 128;
    const int n0 = nblk * 64;
    const int wm = (wave >> 1) * 64;
    const int wn = (wave & 1) * 32;

    const int srow   = lane >> 3;
    const int scol_g = (((lane & 7) ^ srow) << 3);

    f32x4 accz[4][2] = {};
    f32x4 acch[4][2] = {};
    const int lrow = lane & 15;
    const int lcq  = lane >> 4;

    for (int kb = 0; kb < D_; kb += 64) {
        __syncthreads();
        #pragma unroll
        for (int i = 0; i < 4; ++i) {
            int r = i*32 + wave*8;
            async16(&A[(size_t)(m0 + r + srow)*D_ + kb + scol_g], &sm[r*64]);
        }
        #pragma unroll
        for (int i = 0; i < 2; ++i) {
            int r = i*32 + wave*8;
            async16(&Wz[(size_t)(n0 + r + srow)*D_ + kb + scol_g], &sm[8192  + r*64]);
            async16(&Wh[(size_t)(n0 + r + srow)*D_ + kb + scol_g], &sm[12288 + r*64]);
        }
        __syncthreads();
        #pragma unroll
        for (int kk = 0; kk < 64; kk += 32) {
            const int cq = (kk >> 3) + lcq;
            bf16x8 af[4];
            #pragma unroll
            for (int mt = 0; mt < 4; ++mt) {
                int R = wm + mt*16 + lrow;
                uint4 u = *(const uint4*)&sm[SWZ(R, cq)];
                af[mt] = __builtin_bit_cast(bf16x8, u);
            }
            #pragma unroll
            for (int nt = 0; nt < 2; ++nt) {
                int R = wn + nt*16 + lrow;
                uint4 uz = *(const uint4*)&sm[8192  + SWZ(R, cq)];
                uint4 uh = *(const uint4*)&sm[12288 + SWZ(R, cq)];
                bf16x8 zb = __builtin_bit_cast(bf16x8, uz);
                bf16x8 hb = __builtin_bit_cast(bf16x8, uh);
                #pragma unroll
                for (int mt = 0; mt < 4; ++mt) {
                    accz[mt][nt] = MFMA16(af[mt], zb, accz[mt][nt], 0, 0, 0);
                    acch[mt][nt] = MFMA16(af[mt], hb, acch[mt][nt], 0, 0, 0);
                }
            }
        }
    }

    __syncthreads();
    float2* seg = (float2*)sm;
    const int colq = lane & 15;
    const int rowq = (lane >> 4) << 2;
    #pragma unroll
    for (int nt = 0; nt < 2; ++nt) {
        const int n = n0 + wn + nt*16 + colq;
        const float bzv = bz[n];
        const float bhv = bh[n];
        #pragma unroll
        for (int mt = 0; mt < 4; ++mt) {
            float a = 1.f, bb = 0.f;
            h8 pk;
            #pragma unroll
            for (int r = 0; r < 4; ++r) {
                float kx = accz[mt][nt][r] + bzv;
                float p  = acch[mt][nt][r] + bhv;
                float e   = __expf(-fabsf(kx));
                float inv = 1.0f / (1.0f + e);
                float z   = (kx >= 0.f) ? inv     : e * inv;
                float c   = (kx >= 0.f) ? e * inv : inv;
                float g;
                if (p >= 0.f) g = p + 0.5f;
                else { float eg = __expf(p); g = eg / (1.0f + eg); }
                float v = z * g;
                pk[2*r]     = (_Float16)c;
                pk[2*r + 1] = (_Float16)v;
                bb = fmaf(c, bb, v);
                a *= c;
            }
            const int mb4 = (m0 + wm + mt*16 + rowq) >> 2;
            *(h8*)&cv[((size_t)mb4 * H_ + n) * 4] = pk;
            const int sidx = (wm >> 2) + mt*4 + (rowq >> 2);
            seg[sidx*65 + wn + nt*16 + colq] = make_float2(a, bb);
        }
    }
    __syncthreads();
    if (t < 128) {
        const int col  = t & 63;
        const int half = t >> 6;
        float a = 1.f, bb = 0.f;
        #pragma unroll
        for (int s = 0; s < 16; ++s) {
            float2 e2 = seg[(half*16 + s)*65 + col];
            bb = fmaf(e2.x, bb, e2.y);
            a *= e2.x;
        }
        const int b     = m0 >> 11;
        const int chunk = ((m0 >> 6) & (NC - 1)) + half;
        const int q = (b*NC + chunk)*H_ + n0 + col;
        Ac[q] = a; Bc[q] = bb;
    }
}

__global__ __launch_bounds__(256) void scan_emit_fb(const h2* __restrict__ cv,
                                                    const float* __restrict__ Ac,
                                                    const float* __restrict__ Bc,
                                                    float* __restrict__ outf,
                                                    ushort* __restrict__ outb,
                                                    const int write_bf16)
{
    int q = blockIdx.x * 256 + threadIdx.x;          // 0 .. B*NC*H-1
    int h = q & (H_-1);
    int c = (q >> 10) & (NC-1);
    int b = q >> 15;
    float hc = 0.5f;
    for (int cp = 0; cp < c; ++cp) {
        int idx = (b*NC + cp)*H_ + h;
        hc = fmaf(Ac[idx], hc, Bc[idx]);
    }
    const int mb = b*S_ + c*CL;
    if (write_bf16) {
        #pragma unroll 4
        for (int j = 0; j < 16; ++j) {
            h8 e = *(const h8*)&cv[(((size_t)(mb >> 2) + j)*H_ + h) * 4];
            #pragma unroll
            for (int u = 0; u < 4; ++u) {
                hc = fmaf((float)e[2*u], hc, (float)e[2*u + 1]);
                outb[(size_t)(mb + 4*j + u)*H_ + h] = f2bf(hc);
            }
        }
    } else {
        #pragma unroll 4
        for (int j = 0; j < 16; ++j) {
            h8 e = *(const h8*)&cv[(((size_t)(mb >> 2) + j)*H_ + h) * 4];
            #pragma unroll
            for (int u = 0; u < 4; ++u) {
                hc = fmaf((float)e[2*u], hc, (float)e[2*u + 1]);
                outf[(size_t)(mb + 4*j + u)*H_ + h] = hc;
            }
        }
    }
}

extern "C" void kernel_launch(void* const* d_in, const int* in_sizes, int n_in,
                              void* d_out, int out_size, void* d_ws, size_t ws_size,
                              hipStream_t stream)
{
    const float* x  = (const float*)d_in[0];
    const float* Wz = (const float*)d_in[1];
    const float* bz = (const float*)d_in[2];
    const float* Wh = (const float*)d_in[3];
    const float* bh = (const float*)d_in[4];
    float* out = (float*)d_out;

    // workspace (~107 MiB)
    ushort* xb  = (ushort*)d_ws;                      // M*D bf16        (32 MiB)
    ushort* wzb = xb  + (size_t)M_*D_;                // L*H*D bf16      (4 MiB)
    ushort* whb = wzb + (size_t)L_*H_*D_;             // L*H*D bf16      (4 MiB)
    h2*     cv  = (h2*)(whb + (size_t)L_*H_*D_);      // M*H fp16x2      (64 MiB)
    float*  Ac  = (float*)(cv + (size_t)M_*H_);       // B*NC*H          (1 MiB)
    float*  Bc  = Ac + B_*NC*H_;

    // capture-safe one-time occupancy gate for the cooperative path
    static int coop_ok = -1;
    if (coop_ok < 0) {
        int nb = 0;
        hipError_t e = hipOccupancyMaxActiveBlocksPerMultiprocessor(
            &nb, reinterpret_cast<const void*>(mingru_layer), 256, (size_t)0);
        coop_ok = (e == hipSuccess && nb >= 2) ? 1 : 0;
    }

    cast_all<<<(M_*D_/4)/256, 256, 0, stream>>>(x, Wz, Wh, xb, wzb, whb);

    if (coop_ok) {
        for (int l = 0; l < L_; ++l) {
            const ushort* A_  = xb;
            const ushort* Wz_ = wzb + (size_t)l*H_*D_;
            const ushort* Wh_ = whb + (size_t)l*H_*D_;
            const float*  bz_ = bz + l*H_;
            const float*  bh_ = bh + l*H_;
            h2*     cv_ = cv;
            float*  Ac_ = Ac;
            float*  Bc_ = Bc;
            float*  of_ = out;
            ushort* ob_ = xb;
            int wb = (l == 0) ? 1 : 0;
            void* args[] = {&A_, &Wz_, &Wh_, &bz_, &bh_, &cv_, &Ac_, &Bc_,
                            &of_, &ob_, &wb};
            hipLaunchCooperativeKernel(reinterpret_cast<const void*>(mingru_layer),
                                       dim3(512), dim3(256), args, 0, stream);
        }
    } else {
        const int gemm_grid = (M_/128) * (H_/64);    // 2048 blocks
        for (int l = 0; l < L_; ++l) {
            gemm_fb<<<gemm_grid, 256, 0, stream>>>(xb,
                                                   wzb + (size_t)l*H_*D_,
                                                   whb + (size_t)l*H_*D_,
                                                   bz + l*H_, bh + l*H_,
                                                   cv, Ac, Bc);
            scan_emit_fb<<<(B_*NC*H_)/256, 256, 0, stream>>>(cv, Ac, Bc, out, xb,
                                                             (l == 0) ? 1 : 0);
        }
    }
}

// Round 8
// 326.333 us; speedup vs baseline: 1.0301x; 1.0301x over previous
//
#include <hip/hip_runtime.h>
#include <hip/hip_bf16.h>
#include <hip/hip_cooperative_groups.h>

// MinGRU: L=2 layers of  h_t = (1-z_t) h_{t-1} + z_t g(pre_t)
// R11: K-loop is LDS-READ-VOLUME-bound (R3: 128KB/CU/K-step @85B/cyc = 1540cyc
//      = 82us wall; MFMA only 310cyc).  Reduce bytes/output: tile 256m x 64n
//      (dual Z/H), 4 waves as 4m x 1n (each wave = 64 rows x full n) ->
//      96KB per 256x128 output = 3.0 B/out vs R3's 4.0.  Same accumulation
//      order -> bit-identical.  Coop wrapper / Phase C / cast / fallback = R9.

#define L_ 2
#define B_ 8
#define S_ 2048
#define D_ 1024
#define H_ 1024
#define M_ (B_*S_)     // 16384
#define NC 32          // chunks per sequence
#define CL (S_/NC)     // 64 steps per chunk

typedef __bf16    bf16x8 __attribute__((ext_vector_type(8)));
typedef float     f32x4  __attribute__((ext_vector_type(4)));
typedef _Float16  h2     __attribute__((ext_vector_type(2)));
typedef _Float16  h8     __attribute__((ext_vector_type(8)));

__device__ __forceinline__ ushort f2bf(float f) {
    union { __hip_bfloat16 h; ushort u; } c;
    c.h = __float2bfloat16(f);   // RNE
    return c.u;
}

__device__ __forceinline__ void async16(const void* g, void* l) {
    __builtin_amdgcn_global_load_lds(
        (const __attribute__((address_space(1))) unsigned int*)g,
        (__attribute__((address_space(3))) unsigned int*)l, 16, 0, 0);
}

// Single fused cast: x (M*D f32->bf16) and, for the low i-range, Wz/Wh too.
__global__ __launch_bounds__(256) void cast_all(const float* __restrict__ x,
                                                const float* __restrict__ Wz,
                                                const float* __restrict__ Wh,
                                                ushort* __restrict__ xb,
                                                ushort* __restrict__ wzb,
                                                ushort* __restrict__ whb) {
    const int nw = L_*H_*D_/4;                       // 524288
    int i = blockIdx.x * 256 + threadIdx.x;          // grid covers M_*D_/4
    {
        float4 v = ((const float4*)x)[i];
        ushort4 o;
        o.x = f2bf(v.x); o.y = f2bf(v.y); o.z = f2bf(v.z); o.w = f2bf(v.w);
        ((ushort4*)xb)[i] = o;
    }
    if (i < nw) {
        float4 v = ((const float4*)Wz)[i];
        ushort4 o;
        o.x = f2bf(v.x); o.y = f2bf(v.y); o.z = f2bf(v.z); o.w = f2bf(v.w);
        ((ushort4*)wzb)[i] = o;
        float4 w = ((const float4*)Wh)[i];
        ushort4 p;
        p.x = f2bf(w.x); p.y = f2bf(w.y); p.z = f2bf(w.z); p.w = f2bf(w.w);
        ((ushort4*)whb)[i] = p;
    }
}

// LDS layout (staging): row R = 64 ushorts (8 chunks of 16B); logical chunk c
// stored at physical chunk c ^ (R&7).  Offset in ushorts:
#define SWZ(R, c) (((R) << 6) + ((((c) ^ ((R) & 7))) << 3))
#define MFMA16 __builtin_amdgcn_mfma_f32_16x16x32_bf16

// ======================= cooperative single-kernel path =====================
// 512 blocks x 256 thr, 2 blocks/CU (static LDS 48 KiB, launch_bounds(256,2)).
// Tile: 256m x 64n, dual GEMM (Z,H).  4 waves = 4m x 1n: wave w owns rows
// [w*64, w*64+64) x all 64 n-cols.  LDS reads/K-step/block: A 32KB x1(wave) +
// Z 8KB x4 + H 8KB x4 = 96KB per 256x128 output (R3: 64KB per 128x128).
// Phase A: rep=0..1, bid2 = blockIdx + rep*512 -> 1024 tiles (64 mblk x 16 n).
// grid.sync(); Phase C: R6's fused chunk-prefix + replay + emit (2/thread).
__global__ __launch_bounds__(256, 2) void mingru_layer(const ushort* A,
                                                       const ushort* __restrict__ Wz,
                                                       const ushort* __restrict__ Wh,
                                                       const float* __restrict__ bz,
                                                       const float* __restrict__ bh,
                                                       h2* __restrict__ cv,
                                                       float* Ac,
                                                       float* Bc,
                                                       float* outf,
                                                       ushort* outb,
                                                       int write_bf16)
{
    __shared__ __align__(16) ushort sm[24576];       // 48 KiB static

    const int t    = threadIdx.x;
    const int lane = t & 63;
    const int wave = t >> 6;                         // 0..3
    const int lrow = lane & 15;
    const int lcq  = lane >> 4;                      // 0..3
    const int srow   = lane >> 3;                    // 0..7
    const int scol_g = (((lane & 7) ^ srow) << 3);   // swizzled source chunk
    const int colq = lane & 15;
    const int rowq = (lane >> 4) << 2;
    const int wm = wave << 6;                        // wave's 64-row slice

    // ---------------- Phase A: 2 reps of the 256x64 dual GEMM ----------------
    for (int rep = 0; rep < 2; ++rep) {
        const int bid2 = (int)blockIdx.x + (rep << 9);   // 0..1023
        const int xcd = bid2 & 7;
        const int k8  = bid2 >> 3;                   // 0..127
        const int nblk = k8 & 15;                    // 0..15
        const int mblk = ((k8 >> 4) << 3) + xcd;     // 0..63
        const int m0 = mblk * 256;
        const int n0 = nblk * 64;

        f32x4 accz[4][4] = {};
        f32x4 acch[4][4] = {};

        for (int kb = 0; kb < D_; kb += 64) {
            __syncthreads();
            #pragma unroll
            for (int i = 0; i < 8; ++i) {            // A: 256 rows
                int r = i*32 + wave*8;
                async16(&A[(size_t)(m0 + r + srow)*D_ + kb + scol_g], &sm[r*64]);
            }
            #pragma unroll
            for (int i = 0; i < 2; ++i) {            // Wz, Wh: 64 rows each
                int r = i*32 + wave*8;
                async16(&Wz[(size_t)(n0 + r + srow)*D_ + kb + scol_g], &sm[16384 + r*64]);
                async16(&Wh[(size_t)(n0 + r + srow)*D_ + kb + scol_g], &sm[20480 + r*64]);
            }
            __syncthreads();                         // drains vmcnt -> LDS valid
            #pragma unroll
            for (int kk = 0; kk < 2; ++kk) {
                const int cq = kk*4 + lcq;           // logical chunk 0..7
                bf16x8 af[4];
                #pragma unroll
                for (int mt = 0; mt < 4; ++mt) {
                    int R = wm + mt*16 + lrow;
                    uint4 u = *(const uint4*)&sm[SWZ(R, cq)];
                    af[mt] = __builtin_bit_cast(bf16x8, u);
                }
                #pragma unroll
                for (int nt = 0; nt < 4; ++nt) {
                    int R = nt*16 + lrow;
                    uint4 uz = *(const uint4*)&sm[16384 + SWZ(R, cq)];
                    uint4 uh = *(const uint4*)&sm[20480 + SWZ(R, cq)];
                    bf16x8 zb = __builtin_bit_cast(bf16x8, uz);
                    bf16x8 hb = __builtin_bit_cast(bf16x8, uh);
                    #pragma unroll
                    for (int mt = 0; mt < 4; ++mt) {
                        accz[mt][nt] = MFMA16(af[mt], zb, accz[mt][nt], 0, 0, 0);
                        acch[mt][nt] = MFMA16(af[mt], hb, acch[mt][nt], 0, 0, 0);
                    }
                }
            }
        }

        __syncthreads();                             // MFMA LDS reads done
        float2* seg = (float2*)sm;                   // [64 segs][stride 65]
        #pragma unroll
        for (int nt = 0; nt < 4; ++nt) {
            const int n = n0 + nt*16 + colq;
            const float bzv = bz[n];
            const float bhv = bh[n];
            #pragma unroll
            for (int mt = 0; mt < 4; ++mt) {
                float a = 1.f, bb = 0.f;             // affine over lane's 4 rows
                h8 pk;
                #pragma unroll
                for (int r = 0; r < 4; ++r) {
                    float kx = accz[mt][nt][r] + bzv;
                    float p  = acch[mt][nt][r] + bhv;
                    float e   = __expf(-fabsf(kx));
                    float inv = 1.0f / (1.0f + e);
                    float z   = (kx >= 0.f) ? inv     : e * inv;
                    float c   = (kx >= 0.f) ? e * inv : inv;
                    float g;
                    if (p >= 0.f) g = p + 0.5f;
                    else { float eg = __expf(p); g = eg / (1.0f + eg); }
                    float v = z * g;
                    pk[2*r]     = (_Float16)c;
                    pk[2*r + 1] = (_Float16)v;
                    bb = fmaf(c, bb, v);
                    a *= c;
                }
                const int mb4 = (m0 + wm + mt*16 + rowq) >> 2;   // m&3 == r
                *(h8*)&cv[((size_t)mb4 * H_ + n) * 4] = pk;      // 16B coalesced
                const int sidx = (wm >> 2) + mt*4 + (rowq >> 2); // 0..63
                seg[sidx*65 + nt*16 + colq] = make_float2(a, bb);
            }
        }
        __syncthreads();
        {                                            // chunk affines: 4 chunks
            const int col = t & 63;
            const int ch  = t >> 6;                  // 0..3
            float a = 1.f, bb = 0.f;
            #pragma unroll
            for (int s = 0; s < 16; ++s) {
                float2 e2 = seg[(ch*16 + s)*65 + col];
                bb = fmaf(e2.x, bb, e2.y);
                a *= e2.x;
            }
            const int b     = m0 >> 11;              // S = 2048
            const int chunk = ((m0 >> 6) & (NC - 1)) + ch;
            const int qi = (b*NC + chunk)*H_ + n0 + col;
            Ac[qi] = a; Bc[qi] = bb;
        }
        // next rep's K-loop starts with __syncthreads -> seg reads complete
    }

    __threadfence();                                 // release cv/Ac/Bc
    cooperative_groups::this_grid().sync();

    // ---------------- Phase C: fused chunk-prefix + replay + emit ----------
    #pragma unroll
    for (int rep = 0; rep < 2; ++rep) {
        const int q = (int)blockIdx.x * 256 + t + rep * 131072;  // 0..262143
        const int h = q & (H_-1);
        const int c = (q >> 10) & (NC-1);
        const int b = q >> 15;
        float hc = 0.5f;                             // h0 = g(0) = 0.5
        for (int cp = 0; cp < c; ++cp) {
            int idx = (b*NC + cp)*H_ + h;
            hc = fmaf(Ac[idx], hc, Bc[idx]);
        }
        const int mb = b*S_ + c*CL;                  // base row (multiple of 4)
        if (write_bf16) {
            #pragma unroll 4
            for (int j = 0; j < 16; ++j) {
                h8 e = *(const h8*)&cv[(((size_t)(mb >> 2) + j)*H_ + h) * 4];
                #pragma unroll
                for (int u = 0; u < 4; ++u) {
                    hc = fmaf((float)e[2*u], hc, (float)e[2*u + 1]);
                    outb[(size_t)(mb + 4*j + u)*H_ + h] = f2bf(hc);
                }
            }
        } else {
            #pragma unroll 4
            for (int j = 0; j < 16; ++j) {
                h8 e = *(const h8*)&cv[(((size_t)(mb >> 2) + j)*H_ + h) * 4];
                #pragma unroll
                for (int u = 0; u < 4; ++u) {
                    hc = fmaf((float)e[2*u], hc, (float)e[2*u + 1]);
                    outf[(size_t)(mb + 4*j + u)*H_ + h] = hc;
                }
            }
        }
    }
}

// =========================== fallback path (R3/R6) ==========================
__global__ __launch_bounds__(256) void gemm_fb(const ushort* __restrict__ A,
                                               const ushort* __restrict__ Wz,
                                               const ushort* __restrict__ Wh,
                                               const float* __restrict__ bz,
                                               const float* __restrict__ bh,
                                               h2* __restrict__ cv,
                                               float* __restrict__ Ac,
                                               float* __restrict__ Bc)
{
    __shared__ __align__(16) ushort sm[16384];       // 32 KiB

    const int t    = threadIdx.x;
    const int lane = t & 63;
    const int wave = t >> 6;
    const int xcd = (int)blockIdx.x & 7;
    const int k8  = (int)blockIdx.x >> 3;            // 0..255
    const int nblk = k8 & 15;
    const int mblk = ((k8 >> 4) << 3) + xcd;         // 0..127
    const int m0 = mblk * 128;
    const int n0 = nblk * 64;
    const int wm = (wave >> 1) * 64;
    const int wn = (wave & 1) * 32;

    const int srow   = lane >> 3;
    const int scol_g = (((lane & 7) ^ srow) << 3);

    f32x4 accz[4][2] = {};
    f32x4 acch[4][2] = {};
    const int lrow = lane & 15;
    const int lcq  = lane >> 4;

    for (int kb = 0; kb < D_; kb += 64) {
        __syncthreads();
        #pragma unroll
        for (int i = 0; i < 4; ++i) {
            int r = i*32 + wave*8;
            async16(&A[(size_t)(m0 + r + srow)*D_ + kb + scol_g], &sm[r*64]);
        }
        #pragma unroll
        for (int i = 0; i < 2; ++i) {
            int r = i*32 + wave*8;
            async16(&Wz[(size_t)(n0 + r + srow)*D_ + kb + scol_g], &sm[8192  + r*64]);
            async16(&Wh[(size_t)(n0 + r + srow)*D_ + kb + scol_g], &sm[12288 + r*64]);
        }
        __syncthreads();
        #pragma unroll
        for (int kk = 0; kk < 64; kk += 32) {
            const int cq = (kk >> 3) + lcq;
            bf16x8 af[4];
            #pragma unroll
            for (int mt = 0; mt < 4; ++mt) {
                int R = wm + mt*16 + lrow;
                uint4 u = *(const uint4*)&sm[SWZ(R, cq)];
                af[mt] = __builtin_bit_cast(bf16x8, u);
            }
            #pragma unroll
            for (int nt = 0; nt < 2; ++nt) {
                int R = wn + nt*16 + lrow;
                uint4 uz = *(const uint4*)&sm[8192  + SWZ(R, cq)];
                uint4 uh = *(const uint4*)&sm[12288 + SWZ(R, cq)];
                bf16x8 zb = __builtin_bit_cast(bf16x8, uz);
                bf16x8 hb = __builtin_bit_cast(bf16x8, uh);
                #pragma unroll
                for (int mt = 0; mt < 4; ++mt) {
                    accz[mt][nt] = MFMA16(af[mt], zb, accz[mt][nt], 0, 0, 0);
                    acch[mt][nt] = MFMA16(af[mt], hb, acch[mt][nt], 0, 0, 0);
                }
            }
        }
    }

    __syncthreads();
    float2* seg = (float2*)sm;
    const int colq = lane & 15;
    const int rowq = (lane >> 4) << 2;
    #pragma unroll
    for (int nt = 0; nt < 2; ++nt) {
        const int n = n0 + wn + nt*16 + colq;
        const float bzv = bz[n];
        const float bhv = bh[n];
        #pragma unroll
        for (int mt = 0; mt < 4; ++mt) {
            float a = 1.f, bb = 0.f;
            h8 pk;
            #pragma unroll
            for (int r = 0; r < 4; ++r) {
                float kx = accz[mt][nt][r] + bzv;
                float p  = acch[mt][nt][r] + bhv;
                float e   = __expf(-fabsf(kx));
                float inv = 1.0f / (1.0f + e);
                float z   = (kx >= 0.f) ? inv     : e * inv;
                float c   = (kx >= 0.f) ? e * inv : inv;
                float g;
                if (p >= 0.f) g = p + 0.5f;
                else { float eg = __expf(p); g = eg / (1.0f + eg); }
                float v = z * g;
                pk[2*r]     = (_Float16)c;
                pk[2*r + 1] = (_Float16)v;
                bb = fmaf(c, bb, v);
                a *= c;
            }
            const int mb4 = (m0 + wm + mt*16 + rowq) >> 2;
            *(h8*)&cv[((size_t)mb4 * H_ + n) * 4] = pk;
            const int sidx = (wm >> 2) + mt*4 + (rowq >> 2);
            seg[sidx*65 + wn + nt*16 + colq] = make_float2(a, bb);
        }
    }
    __syncthreads();
    if (t < 128) {
        const int col  = t & 63;
        const int half = t >> 6;
        float a = 1.f, bb = 0.f;
        #pragma unroll
        for (int s = 0; s < 16; ++s) {
            float2 e2 = seg[(half*16 + s)*65 + col];
            bb = fmaf(e2.x, bb, e2.y);
            a *= e2.x;
        }
        const int b     = m0 >> 11;
        const int chunk = ((m0 >> 6) & (NC - 1)) + half;
        const int q = (b*NC + chunk)*H_ + n0 + col;
        Ac[q] = a; Bc[q] = bb;
    }
}

__global__ __launch_bounds__(256) void scan_emit_fb(const h2* __restrict__ cv,
                                                    const float* __restrict__ Ac,
                                                    const float* __restrict__ Bc,
                                                    float* __restrict__ outf,
                                                    ushort* __restrict__ outb,
                                                    const int write_bf16)
{
    int q = blockIdx.x * 256 + threadIdx.x;          // 0 .. B*NC*H-1
    int h = q & (H_-1);
    int c = (q >> 10) & (NC-1);
    int b = q >> 15;
    float hc = 0.5f;
    for (int cp = 0; cp < c; ++cp) {
        int idx = (b*NC + cp)*H_ + h;
        hc = fmaf(Ac[idx], hc, Bc[idx]);
    }
    const int mb = b*S_ + c*CL;
    if (write_bf16) {
        #pragma unroll 4
        for (int j = 0; j < 16; ++j) {
            h8 e = *(const h8*)&cv[(((size_t)(mb >> 2) + j)*H_ + h) * 4];
            #pragma unroll
            for (int u = 0; u < 4; ++u) {
                hc = fmaf((float)e[2*u], hc, (float)e[2*u + 1]);
                outb[(size_t)(mb + 4*j + u)*H_ + h] = f2bf(hc);
            }
        }
    } else {
        #pragma unroll 4
        for (int j = 0; j < 16; ++j) {
            h8 e = *(const h8*)&cv[(((size_t)(mb >> 2) + j)*H_ + h) * 4];
            #pragma unroll
            for (int u = 0; u < 4; ++u) {
                hc = fmaf((float)e[2*u], hc, (float)e[2*u + 1]);
                outf[(size_t)(mb + 4*j + u)*H_ + h] = hc;
            }
        }
    }
}

extern "C" void kernel_launch(void* const* d_in, const int* in_sizes, int n_in,
                              void* d_out, int out_size, void* d_ws, size_t ws_size,
                              hipStream_t stream)
{
    const float* x  = (const float*)d_in[0];
    const float* Wz = (const float*)d_in[1];
    const float* bz = (const float*)d_in[2];
    const float* Wh = (const float*)d_in[3];
    const float* bh = (const float*)d_in[4];
    float* out = (float*)d_out;

    // workspace (~107 MiB)
    ushort* xb  = (ushort*)d_ws;                      // M*D bf16        (32 MiB)
    ushort* wzb = xb  + (size_t)M_*D_;                // L*H*D bf16      (4 MiB)
    ushort* whb = wzb + (size_t)L_*H_*D_;             // L*H*D bf16      (4 MiB)
    h2*     cv  = (h2*)(whb + (size_t)L_*H_*D_);      // M*H fp16x2      (64 MiB)
    float*  Ac  = (float*)(cv + (size_t)M_*H_);       // B*NC*H          (1 MiB)
    float*  Bc  = Ac + B_*NC*H_;

    // capture-safe one-time occupancy gate for the cooperative path
    static int coop_ok = -1;
    if (coop_ok < 0) {
        int nb = 0;
        hipError_t e = hipOccupancyMaxActiveBlocksPerMultiprocessor(
            &nb, reinterpret_cast<const void*>(mingru_layer), 256, (size_t)0);
        coop_ok = (e == hipSuccess && nb >= 2) ? 1 : 0;
    }

    cast_all<<<(M_*D_/4)/256, 256, 0, stream>>>(x, Wz, Wh, xb, wzb, whb);

    if (coop_ok) {
        for (int l = 0; l < L_; ++l) {
            const ushort* A_  = xb;
            const ushort* Wz_ = wzb + (size_t)l*H_*D_;
            const ushort* Wh_ = whb + (size_t)l*H_*D_;
            const float*  bz_ = bz + l*H_;
            const float*  bh_ = bh + l*H_;
            h2*     cv_ = cv;
            float*  Ac_ = Ac;
            float*  Bc_ = Bc;
            float*  of_ = out;
            ushort* ob_ = xb;
            int wb = (l == 0) ? 1 : 0;
            void* args[] = {&A_, &Wz_, &Wh_, &bz_, &bh_, &cv_, &Ac_, &Bc_,
                            &of_, &ob_, &wb};
            hipLaunchCooperativeKernel(reinterpret_cast<const void*>(mingru_layer),
                                       dim3(512), dim3(256), args, 0, stream);
        }
    } else {
        const int gemm_grid = (M_/128) * (H_/64);    // 2048 blocks
        for (int l = 0; l < L_; ++l) {
            gemm_fb<<<gemm_grid, 256, 0, stream>>>(xb,
                                                   wzb + (size_t)l*H_*D_,
                                                   whb + (size_t)l*H_*D_,
                                                   bz + l*H_, bh + l*H_,
                                                   cv, Ac, Bc);
            scan_emit_fb<<<(B_*NC*H_)/256, 256, 0, stream>>>(cv, Ac, Bc, out, xb,
                                                             (l == 0) ? 1 : 0);
        }
    }
}

// Round 9
// 323.834 us; speedup vs baseline: 1.0381x; 1.0077x over previous
//
#include <hip/hip_runtime.h>
#include <hip/hip_bf16.h>
#include <hip/hip_cooperative_groups.h>

// MinGRU: L=2 layers of  h_t = (1-z_t) h_{t-1} + z_t g(pre_t)
// R12: in R11's 4m x 1n wave decomposition each A-row is consumed by exactly
//      ONE wave -> staging A through LDS is pure overhead (32KB write + 32KB
//      read per block-K-step, zero sharing). Stream A global->VGPR with
//      per-lane fragment addresses (bytes identical to the LDS path ->
//      bit-identical output); only Z/H (shared by 4 waves) stay in LDS.
//      LDS reads 96->64KB, writes 48->16KB per block-K-step; global traffic
//      unchanged (A was L2-fetched either way; cf. R10 wash on B which IS
//      VMEM-amplified 4x). LDS block 48->32KB. Rest = R11 verbatim.

#define L_ 2
#define B_ 8
#define S_ 2048
#define D_ 1024
#define H_ 1024
#define M_ (B_*S_)     // 16384
#define NC 32          // chunks per sequence
#define CL (S_/NC)     // 64 steps per chunk

typedef __bf16    bf16x8 __attribute__((ext_vector_type(8)));
typedef float     f32x4  __attribute__((ext_vector_type(4)));
typedef _Float16  h2     __attribute__((ext_vector_type(2)));
typedef _Float16  h8     __attribute__((ext_vector_type(8)));

__device__ __forceinline__ ushort f2bf(float f) {
    union { __hip_bfloat16 h; ushort u; } c;
    c.h = __float2bfloat16(f);   // RNE
    return c.u;
}

__device__ __forceinline__ void async16(const void* g, void* l) {
    __builtin_amdgcn_global_load_lds(
        (const __attribute__((address_space(1))) unsigned int*)g,
        (__attribute__((address_space(3))) unsigned int*)l, 16, 0, 0);
}

// Single fused cast: x (M*D f32->bf16) and, for the low i-range, Wz/Wh too.
__global__ __launch_bounds__(256) void cast_all(const float* __restrict__ x,
                                                const float* __restrict__ Wz,
                                                const float* __restrict__ Wh,
                                                ushort* __restrict__ xb,
                                                ushort* __restrict__ wzb,
                                                ushort* __restrict__ whb) {
    const int nw = L_*H_*D_/4;                       // 524288
    int i = blockIdx.x * 256 + threadIdx.x;          // grid covers M_*D_/4
    {
        float4 v = ((const float4*)x)[i];
        ushort4 o;
        o.x = f2bf(v.x); o.y = f2bf(v.y); o.z = f2bf(v.z); o.w = f2bf(v.w);
        ((ushort4*)xb)[i] = o;
    }
    if (i < nw) {
        float4 v = ((const float4*)Wz)[i];
        ushort4 o;
        o.x = f2bf(v.x); o.y = f2bf(v.y); o.z = f2bf(v.z); o.w = f2bf(v.w);
        ((ushort4*)wzb)[i] = o;
        float4 w = ((const float4*)Wh)[i];
        ushort4 p;
        p.x = f2bf(w.x); p.y = f2bf(w.y); p.z = f2bf(w.z); p.w = f2bf(w.w);
        ((ushort4*)whb)[i] = p;
    }
}

// LDS layout (staging): row R = 64 ushorts (8 chunks of 16B); logical chunk c
// stored at physical chunk c ^ (R&7).  Offset in ushorts:
#define SWZ(R, c) (((R) << 6) + ((((c) ^ ((R) & 7))) << 3))
#define MFMA16 __builtin_amdgcn_mfma_f32_16x16x32_bf16

// ======================= cooperative single-kernel path =====================
// 512 blocks x 256 thr, 2 blocks/CU (static LDS 32 KiB, launch_bounds(256,2)).
// Tile: 256m x 64n dual (Z,H).  4 waves = 4m x 1n; wave w owns rows
// [w*64,w*64+64) -> A rows are wave-private -> A streamed global->VGPR.
// LDS: Zs 64x64 @0, Hs @4096 (ushorts); epilogue seg = [64][64] float2 (32KB).
// Phase A: rep=0..1, bid2 = blockIdx + rep*512 -> 1024 tiles (64 mblk x 16 n).
// grid.sync(); Phase C: fused chunk-prefix + replay + emit (2 items/thread).
__global__ __launch_bounds__(256, 2) void mingru_layer(const ushort* A,
                                                       const ushort* __restrict__ Wz,
                                                       const ushort* __restrict__ Wh,
                                                       const float* __restrict__ bz,
                                                       const float* __restrict__ bh,
                                                       h2* __restrict__ cv,
                                                       float* Ac,
                                                       float* Bc,
                                                       float* outf,
                                                       ushort* outb,
                                                       int write_bf16)
{
    __shared__ __align__(16) ushort sm[16384];       // 32 KiB static

    const int t    = threadIdx.x;
    const int lane = t & 63;
    const int wave = t >> 6;                         // 0..3
    const int lrow = lane & 15;
    const int lcq  = lane >> 4;                      // 0..3
    const int srow   = lane >> 3;                    // 0..7
    const int scol_g = (((lane & 7) ^ srow) << 3);   // swizzled source chunk
    const int colq = lane & 15;
    const int rowq = (lane >> 4) << 2;
    const int wm = wave << 6;                        // wave's 64-row slice

    // ---------------- Phase A: 2 reps of the 256x64 dual GEMM ----------------
    for (int rep = 0; rep < 2; ++rep) {
        const int bid2 = (int)blockIdx.x + (rep << 9);   // 0..1023
        const int xcd = bid2 & 7;
        const int k8  = bid2 >> 3;                   // 0..127
        const int nblk = k8 & 15;                    // 0..15
        const int mblk = ((k8 >> 4) << 3) + xcd;     // 0..63
        const int m0 = mblk * 256;
        const int n0 = nblk * 64;

        f32x4 accz[4][4] = {};
        f32x4 acch[4][4] = {};

        for (int kb = 0; kb < D_; kb += 64) {
            // A fragments straight from global (L2-hot; rows wave-private).
            // Bytes identical to the old LDS path:
            //   A[(m0+wm+mt*16+lrow)*D + kb + (kk*4+lcq)*8], 16B/lane.
            uint4 areg[2][4];                        // [kk][mt], 32 VGPR
            #pragma unroll
            for (int kk = 0; kk < 2; ++kk)
                #pragma unroll
                for (int mt = 0; mt < 4; ++mt) {
                    const size_t ao = (size_t)(m0 + wm + mt*16 + lrow)*D_
                                      + kb + (kk*4 + lcq)*8;
                    areg[kk][mt] = *(const uint4*)&A[ao];
                }
            __syncthreads();                         // prev B ds_reads done
            #pragma unroll
            for (int i = 0; i < 2; ++i) {            // Wz, Wh: 64 rows each
                int r = i*32 + wave*8;
                async16(&Wz[(size_t)(n0 + r + srow)*D_ + kb + scol_g], &sm[r*64]);
                async16(&Wh[(size_t)(n0 + r + srow)*D_ + kb + scol_g], &sm[4096 + r*64]);
            }
            __syncthreads();                         // drains vmcnt -> regs+LDS
            #pragma unroll
            for (int kk = 0; kk < 2; ++kk) {
                const int cq = kk*4 + lcq;           // logical chunk 0..7
                bf16x8 af[4];
                #pragma unroll
                for (int mt = 0; mt < 4; ++mt)
                    af[mt] = __builtin_bit_cast(bf16x8, areg[kk][mt]);
                #pragma unroll
                for (int nt = 0; nt < 4; ++nt) {
                    int R = nt*16 + lrow;
                    uint4 uz = *(const uint4*)&sm[SWZ(R, cq)];
                    uint4 uh = *(const uint4*)&sm[4096 + SWZ(R, cq)];
                    bf16x8 zb = __builtin_bit_cast(bf16x8, uz);
                    bf16x8 hb = __builtin_bit_cast(bf16x8, uh);
                    #pragma unroll
                    for (int mt = 0; mt < 4; ++mt) {
                        accz[mt][nt] = MFMA16(af[mt], zb, accz[mt][nt], 0, 0, 0);
                        acch[mt][nt] = MFMA16(af[mt], hb, acch[mt][nt], 0, 0, 0);
                    }
                }
            }
        }

        __syncthreads();                             // MFMA LDS reads done
        float2* seg = (float2*)sm;                   // [64 segs][stride 64]
        #pragma unroll
        for (int nt = 0; nt < 4; ++nt) {
            const int n = n0 + nt*16 + colq;
            const float bzv = bz[n];
            const float bhv = bh[n];
            #pragma unroll
            for (int mt = 0; mt < 4; ++mt) {
                float a = 1.f, bb = 0.f;             // affine over lane's 4 rows
                h8 pk;
                #pragma unroll
                for (int r = 0; r < 4; ++r) {
                    float kx = accz[mt][nt][r] + bzv;
                    float p  = acch[mt][nt][r] + bhv;
                    float e   = __expf(-fabsf(kx));
                    float inv = 1.0f / (1.0f + e);
                    float z   = (kx >= 0.f) ? inv     : e * inv;
                    float c   = (kx >= 0.f) ? e * inv : inv;
                    float g;
                    if (p >= 0.f) g = p + 0.5f;
                    else { float eg = __expf(p); g = eg / (1.0f + eg); }
                    float v = z * g;
                    pk[2*r]     = (_Float16)c;
                    pk[2*r + 1] = (_Float16)v;
                    bb = fmaf(c, bb, v);
                    a *= c;
                }
                const int mb4 = (m0 + wm + mt*16 + rowq) >> 2;   // m&3 == r
                *(h8*)&cv[((size_t)mb4 * H_ + n) * 4] = pk;      // 16B coalesced
                const int sidx = (wm >> 2) + mt*4 + (rowq >> 2); // 0..63
                seg[sidx*64 + nt*16 + colq] = make_float2(a, bb);
            }
        }
        __syncthreads();
        {                                            // chunk affines: 4 chunks
            const int col = t & 63;
            const int ch  = t >> 6;                  // 0..3
            float a = 1.f, bb = 0.f;
            #pragma unroll
            for (int s = 0; s < 16; ++s) {
                float2 e2 = seg[(ch*16 + s)*64 + col];
                bb = fmaf(e2.x, bb, e2.y);
                a *= e2.x;
            }
            const int b     = m0 >> 11;              // S = 2048
            const int chunk = ((m0 >> 6) & (NC - 1)) + ch;
            const int qi = (b*NC + chunk)*H_ + n0 + col;
            Ac[qi] = a; Bc[qi] = bb;
        }
        // next rep's K-loop starts with __syncthreads -> seg reads complete
    }

    __threadfence();                                 // release cv/Ac/Bc
    cooperative_groups::this_grid().sync();

    // ---------------- Phase C: fused chunk-prefix + replay + emit ----------
    #pragma unroll
    for (int rep = 0; rep < 2; ++rep) {
        const int q = (int)blockIdx.x * 256 + t + rep * 131072;  // 0..262143
        const int h = q & (H_-1);
        const int c = (q >> 10) & (NC-1);
        const int b = q >> 15;
        float hc = 0.5f;                             // h0 = g(0) = 0.5
        for (int cp = 0; cp < c; ++cp) {
            int idx = (b*NC + cp)*H_ + h;
            hc = fmaf(Ac[idx], hc, Bc[idx]);
        }
        const int mb = b*S_ + c*CL;                  // base row (multiple of 4)
        if (write_bf16) {
            #pragma unroll 4
            for (int j = 0; j < 16; ++j) {
                h8 e = *(const h8*)&cv[(((size_t)(mb >> 2) + j)*H_ + h) * 4];
                #pragma unroll
                for (int u = 0; u < 4; ++u) {
                    hc = fmaf((float)e[2*u], hc, (float)e[2*u + 1]);
                    outb[(size_t)(mb + 4*j + u)*H_ + h] = f2bf(hc);
                }
            }
        } else {
            #pragma unroll 4
            for (int j = 0; j < 16; ++j) {
                h8 e = *(const h8*)&cv[(((size_t)(mb >> 2) + j)*H_ + h) * 4];
                #pragma unroll
                for (int u = 0; u < 4; ++u) {
                    hc = fmaf((float)e[2*u], hc, (float)e[2*u + 1]);
                    outf[(size_t)(mb + 4*j + u)*H_ + h] = hc;
                }
            }
        }
    }
}

// =========================== fallback path (R3/R6) ==========================
__global__ __launch_bounds__(256) void gemm_fb(const ushort* __restrict__ A,
                                               const ushort* __restrict__ Wz,
                                               const ushort* __restrict__ Wh,
                                               const float* __restrict__ bz,
                                               const float* __restrict__ bh,
                                               h2* __restrict__ cv,
                                               float* __restrict__ Ac,
                                               float* __restrict__ Bc)
{
    __shared__ __align__(16) ushort sm[16384];       // 32 KiB

    const int t    = threadIdx.x;
    const int lane = t & 63;
    const int wave = t >> 6;
    const int xcd = (int)blockIdx.x & 7;
    const int k8  = (int)blockIdx.x >> 3;            // 0..255
    const int nblk = k8 & 15;
    const int mblk = ((k8 >> 4) << 3) + xcd;         // 0..127
    const int m0 = mblk * 128;
    const int n0 = nblk * 64;
    const int wm = (wave >> 1) * 64;
    const int wn = (wave & 1) * 32;

    const int srow   = lane >> 3;
    const int scol_g = (((lane & 7) ^ srow) << 3);

    f32x4 accz[4][2] = {};
    f32x4 acch[4][2] = {};
    const int lrow = lane & 15;
    const int lcq  = lane >> 4;

    for (int kb = 0; kb < D_; kb += 64) {
        __syncthreads();
        #pragma unroll
        for (int i = 0; i < 4; ++i) {
            int r = i*32 + wave*8;
            async16(&A[(size_t)(m0 + r + srow)*D_ + kb + scol_g], &sm[r*64]);
        }
        #pragma unroll
        for (int i = 0; i < 2; ++i) {
            int r = i*32 + wave*8;
            async16(&Wz[(size_t)(n0 + r + srow)*D_ + kb + scol_g], &sm[8192  + r*64]);
            async16(&Wh[(size_t)(n0 + r + srow)*D_ + kb + scol_g], &sm[12288 + r*64]);
        }
        __syncthreads();
        #pragma unroll
        for (int kk = 0; kk < 64; kk += 32) {
            const int cq = (kk >> 3) + lcq;
            bf16x8 af[4];
            #pragma unroll
            for (int mt = 0; mt < 4; ++mt) {
                int R = wm + mt*16 + lrow;
                uint4 u = *(const uint4*)&sm[SWZ(R, cq)];
                af[mt] = __builtin_bit_cast(bf16x8, u);
            }
            #pragma unroll
            for (int nt = 0; nt < 2; ++nt) {
                int R = wn + nt*16 + lrow;
                uint4 uz = *(const uint4*)&sm[8192  + SWZ(R, cq)];
                uint4 uh = *(const uint4*)&sm[12288 + SWZ(R, cq)];
                bf16x8 zb = __builtin_bit_cast(bf16x8, uz);
                bf16x8 hb = __builtin_bit_cast(bf16x8, uh);
                #pragma unroll
                for (int mt = 0; mt < 4; ++mt) {
                    accz[mt][nt] = MFMA16(af[mt], zb, accz[mt][nt], 0, 0, 0);
                    acch[mt][nt] = MFMA16(af[mt], hb, acch[mt][nt], 0, 0, 0);
                }
            }
        }
    }

    __syncthreads();
    float2* seg = (float2*)sm;
    const int colq = lane & 15;
    const int rowq = (lane >> 4) << 2;
    #pragma unroll
    for (int nt = 0; nt < 2; ++nt) {
        const int n = n0 + wn + nt*16 + colq;
        const float bzv = bz[n];
        const float bhv = bh[n];
        #pragma unroll
        for (int mt = 0; mt < 4; ++mt) {
            float a = 1.f, bb = 0.f;
            h8 pk;
            #pragma unroll
            for (int r = 0; r < 4; ++r) {
                float kx = accz[mt][nt][r] + bzv;
                float p  = acch[mt][nt][r] + bhv;
                float e   = __expf(-fabsf(kx));
                float inv = 1.0f / (1.0f + e);
                float z   = (kx >= 0.f) ? inv     : e * inv;
                float c   = (kx >= 0.f) ? e * inv : inv;
                float g;
                if (p >= 0.f) g = p + 0.5f;
                else { float eg = __expf(p); g = eg / (1.0f + eg); }
                float v = z * g;
                pk[2*r]     = (_Float16)c;
                pk[2*r + 1] = (_Float16)v;
                bb = fmaf(c, bb, v);
                a *= c;
            }
            const int mb4 = (m0 + wm + mt*16 + rowq) >> 2;
            *(h8*)&cv[((size_t)mb4 * H_ + n) * 4] = pk;
            const int sidx = (wm >> 2) + mt*4 + (rowq >> 2);
            seg[sidx*65 + wn + nt*16 + colq] = make_float2(a, bb);
        }
    }
    __syncthreads();
    if (t < 128) {
        const int col  = t & 63;
        const int half = t >> 6;
        float a = 1.f, bb = 0.f;
        #pragma unroll
        for (int s = 0; s < 16; ++s) {
            float2 e2 = seg[(half*16 + s)*65 + col];
            bb = fmaf(e2.x, bb, e2.y);
            a *= e2.x;
        }
        const int b     = m0 >> 11;
        const int chunk = ((m0 >> 6) & (NC - 1)) + half;
        const int q = (b*NC + chunk)*H_ + n0 + col;
        Ac[q] = a; Bc[q] = bb;
    }
}

__global__ __launch_bounds__(256) void scan_emit_fb(const h2* __restrict__ cv,
                                                    const float* __restrict__ Ac,
                                                    const float* __restrict__ Bc,
                                                    float* __restrict__ outf,
                                                    ushort* __restrict__ outb,
                                                    const int write_bf16)
{
    int q = blockIdx.x * 256 + threadIdx.x;          // 0 .. B*NC*H-1
    int h = q & (H_-1);
    int c = (q >> 10) & (NC-1);
    int b = q >> 15;
    float hc = 0.5f;
    for (int cp = 0; cp < c; ++cp) {
        int idx = (b*NC + cp)*H_ + h;
        hc = fmaf(Ac[idx], hc, Bc[idx]);
    }
    const int mb = b*S_ + c*CL;
    if (write_bf16) {
        #pragma unroll 4
        for (int j = 0; j < 16; ++j) {
            h8 e = *(const h8*)&cv[(((size_t)(mb >> 2) + j)*H_ + h) * 4];
            #pragma unroll
            for (int u = 0; u < 4; ++u) {
                hc = fmaf((float)e[2*u], hc, (float)e[2*u + 1]);
                outb[(size_t)(mb + 4*j + u)*H_ + h] = f2bf(hc);
            }
        }
    } else {
        #pragma unroll 4
        for (int j = 0; j < 16; ++j) {
            h8 e = *(const h8*)&cv[(((size_t)(mb >> 2) + j)*H_ + h) * 4];
            #pragma unroll
            for (int u = 0; u < 4; ++u) {
                hc = fmaf((float)e[2*u], hc, (float)e[2*u + 1]);
                outf[(size_t)(mb + 4*j + u)*H_ + h] = hc;
            }
        }
    }
}

extern "C" void kernel_launch(void* const* d_in, const int* in_sizes, int n_in,
                              void* d_out, int out_size, void* d_ws, size_t ws_size,
                              hipStream_t stream)
{
    const float* x  = (const float*)d_in[0];
    const float* Wz = (const float*)d_in[1];
    const float* bz = (const float*)d_in[2];
    const float* Wh = (const float*)d_in[3];
    const float* bh = (const float*)d_in[4];
    float* out = (float*)d_out;

    // workspace (~107 MiB)
    ushort* xb  = (ushort*)d_ws;                      // M*D bf16        (32 MiB)
    ushort* wzb = xb  + (size_t)M_*D_;                // L*H*D bf16      (4 MiB)
    ushort* whb = wzb + (size_t)L_*H_*D_;             // L*H*D bf16      (4 MiB)
    h2*     cv  = (h2*)(whb + (size_t)L_*H_*D_);      // M*H fp16x2      (64 MiB)
    float*  Ac  = (float*)(cv + (size_t)M_*H_);       // B*NC*H          (1 MiB)
    float*  Bc  = Ac + B_*NC*H_;

    // capture-safe one-time occupancy gate for the cooperative path
    static int coop_ok = -1;
    if (coop_ok < 0) {
        int nb = 0;
        hipError_t e = hipOccupancyMaxActiveBlocksPerMultiprocessor(
            &nb, reinterpret_cast<const void*>(mingru_layer), 256, (size_t)0);
        coop_ok = (e == hipSuccess && nb >= 2) ? 1 : 0;
    }

    cast_all<<<(M_*D_/4)/256, 256, 0, stream>>>(x, Wz, Wh, xb, wzb, whb);

    if (coop_ok) {
        for (int l = 0; l < L_; ++l) {
            const ushort* A_  = xb;
            const ushort* Wz_ = wzb + (size_t)l*H_*D_;
            const ushort* Wh_ = whb + (size_t)l*H_*D_;
            const float*  bz_ = bz + l*H_;
            const float*  bh_ = bh + l*H_;
            h2*     cv_ = cv;
            float*  Ac_ = Ac;
            float*  Bc_ = Bc;
            float*  of_ = out;
            ushort* ob_ = xb;
            int wb = (l == 0) ? 1 : 0;
            void* args[] = {&A_, &Wz_, &Wh_, &bz_, &bh_, &cv_, &Ac_, &Bc_,
                            &of_, &ob_, &wb};
            hipLaunchCooperativeKernel(reinterpret_cast<const void*>(mingru_layer),
                                       dim3(512), dim3(256), args, 0, stream);
        }
    } else {
        const int gemm_grid = (M_/128) * (H_/64);    // 2048 blocks
        for (int l = 0; l < L_; ++l) {
            gemm_fb<<<gemm_grid, 256, 0, stream>>>(xb,
                                                   wzb + (size_t)l*H_*D_,
                                                   whb + (size_t)l*H_*D_,
                                                   bz + l*H_, bh + l*H_,
                                                   cv, Ac, Bc);
            scan_emit_fb<<<(B_*NC*H_)/256, 256, 0, stream>>>(cv, Ac, Bc, out, xb,
                                                             (l == 0) ? 1 : 0);
        }
    }
}